// Round 18
// baseline (262.223 us; speedup 1.0000x reference)
//
#include <hip/hip_runtime.h>
#include <math.h>

#define NN 50000
#define NE 800000
#define TW 10
#define SNP 50048          // padded node stride (ints)
#define CAP 80             // padded CSR row capacity (max in-degree ~35 expected)
#define TOTAL_B 2048       // fused edge+conv grid (fully resident)
#define NBLK 2000          // 25-node work blocks for agg kernels
#define LB 196             // lstm blocks

static __device__ __forceinline__ float sigf(float x){ return 1.0f/(1.0f+__expf(-x)); }
static __device__ __forceinline__ float tanhfast(float x){
  float e2 = __expf(2.0f*x);
  return 1.0f - 2.0f/(e2 + 1.0f);
}
// bf16 pack/unpack (RNE)
static __device__ __forceinline__ unsigned f2bf(float f){
  unsigned u = __float_as_uint(f);
  return (u + 0x7FFFu + ((u>>16)&1u)) >> 16;
}
static __device__ __forceinline__ unsigned pack2(float a, float b){
  return f2bf(a) | (f2bf(b) << 16);
}
static __device__ __forceinline__ float bflo(unsigned u){ return __uint_as_float(u << 16); }
static __device__ __forceinline__ float bfhi(unsigned u){ return __uint_as_float(u & 0xFFFF0000u); }
static __device__ __forceinline__ float rdeg(int d){ return rsqrtf((float)(d < 1 ? 1 : d)); }

// ---------------- zero counters + init maxbuf ----------------
#define ZERO_U4 37536   // 3*SNP ints = 600576 B
__global__ void k_zero(uint4* __restrict__ p, unsigned* __restrict__ maxbuf){
  int i = blockIdx.x*256 + threadIdx.x;
  uint4 z; z.x = 0u; z.y = 0u; z.z = 0u; z.w = 0u;
  if (i < ZERO_U4) p[i] = z;
  if (i < 8) maxbuf[i] = 0x3FFFFFFFu;   // monotonic-map(-2.0f)
}

// ======= fused edge+conv: ISSUE atomics early -> conv loop -> dependent stores late =======
// The cursor-atomic results are consumed only AFTER the conv loop, so the
// ~60-90us atomic queue drains underneath conv's HBM streaming.
__global__ __launch_bounds__(256) void k_buildconv(const float* __restrict__ feat,
                                                   const float* __restrict__ W1,
                                                   const int* __restrict__ src,
                                                   const int* __restrict__ dst,
                                                   int* __restrict__ dego,
                                                   int* __restrict__ degi,
                                                   int* __restrict__ csrp,
                                                   uint4* __restrict__ h1){
  int tid = threadIdx.x;
  int gthread = blockIdx.x*256 + tid;

  // ---- phase 1: issue edge atomics (keep slots in VGPRs, no stores, no wait) ----
  int4 sv, dv;
  int p0 = 0, p1 = 0, p2 = 0, p3 = 0;
  bool have = false;
  {
    const int NITEM = NE/4;      // 200000 int4 items; threads >= NITEM have none
    if (gthread < NITEM){
      sv = ((const int4*)src)[gthread];
      dv = ((const int4*)dst)[gthread];
      p0 = atomicAdd(&degi[dv.x], 1);
      p1 = atomicAdd(&degi[dv.y], 1);
      p2 = atomicAdd(&degi[dv.z], 1);
      p3 = atomicAdd(&degi[dv.w], 1);
      atomicAdd(&dego[sv.x], 1);   // fire-and-forget
      atomicAdd(&dego[sv.y], 1);
      atomicAdd(&dego[sv.z], 1);
      atomicAdd(&dego[sv.w], 1);
      have = true;
    }
  }

  // ---- phase 2: conv1 raw (16 lanes per row, weights in VGPRs from global) ----
  int lane = tid & 15;
  float4 wa[8], wb[8];
  #pragma unroll
  for (int d = 0; d < 8; ++d){
    wa[d] = ((const float4*)W1)[(lane*8 + d)*2 + 0];
    wb[d] = ((const float4*)W1)[(lane*8 + d)*2 + 1];
  }
  int gid = gthread >> 4;
  const int ngroups = TOTAL_B*16;
  for (int r = gid; r < TW*NN; r += ngroups){
    const float4* frow = (const float4*)feat + (long long)r*32 + lane*2;
    float4 f0 = frow[0], f1 = frow[1];
    float fs[8] = {f0.x,f0.y,f0.z,f0.w,f1.x,f1.y,f1.z,f1.w};
    float acc[8] = {0,0,0,0,0,0,0,0};
    #pragma unroll
    for (int d = 0; d < 8; ++d){
      float fv = fs[d];
      acc[0] += fv*wa[d].x; acc[1] += fv*wa[d].y; acc[2] += fv*wa[d].z; acc[3] += fv*wa[d].w;
      acc[4] += fv*wb[d].x; acc[5] += fv*wb[d].y; acc[6] += fv*wb[d].z; acc[7] += fv*wb[d].w;
    }
    int b8 = (lane>>3)&1, b4 = (lane>>2)&1, b2 = (lane>>1)&1;
    float s0 = b8 ? acc[0] : acc[4], s1 = b8 ? acc[1] : acc[5];
    float s2 = b8 ? acc[2] : acc[6], s3 = b8 ? acc[3] : acc[7];
    float k0 = b8 ? acc[4] : acc[0], k1 = b8 ? acc[5] : acc[1];
    float k2 = b8 ? acc[6] : acc[2], k3 = b8 ? acc[7] : acc[3];
    k0 += __shfl_xor(s0, 8); k1 += __shfl_xor(s1, 8);
    k2 += __shfl_xor(s2, 8); k3 += __shfl_xor(s3, 8);
    float t0 = b4 ? k0 : k2, t1 = b4 ? k1 : k3;
    float m0 = b4 ? k2 : k0, m1 = b4 ? k3 : k1;
    m0 += __shfl_xor(t0, 4); m1 += __shfl_xor(t1, 4);
    float u1 = b2 ? m0 : m1;
    float v0 = b2 ? m1 : m0;
    v0 += __shfl_xor(u1, 2);
    v0 += __shfl_xor(v0, 1);
    int t = r / NN;
    int n = r - t*NN;
    unsigned u = f2bf(v0) << (b2*16);     // raw: ns applied per-edge in agg1
    u |= __shfl_xor(u, 2);
    if ((lane & 3) == 0){
      int kk = b8*2 + b4;
      ((unsigned*)h1)[((long long)n*10 + t)*4 + kk] = u;
    }
  }

  // ---- phase 3: dependent CSR stores (atomic results long since returned) ----
  if (have){
    if (p0 < CAP) csrp[dv.x*CAP + p0] = sv.x;
    if (p1 < CAP) csrp[dv.y*CAP + p1] = sv.y;
    if (p2 < CAP) csrp[dv.z*CAP + p2] = sv.z;
    if (p3 < CAP) csrp[dv.w*CAP + p3] = sv.w;
  }
}

// ======= gather kernels: block = 25 nodes x 10 windows, padded-CSR rows =======
#define ACC8(v) { a0 += bflo(v.x); a1 += bfhi(v.x); a2 += bflo(v.y); a3 += bfhi(v.y); \
                  a4 += bflo(v.z); a5 += bfhi(v.z); a6 += bflo(v.w); a7 += bfhi(v.w); }
#define ACC8S(v, sc) { a0 = fmaf(sc, bflo(v.x), a0); a1 = fmaf(sc, bfhi(v.x), a1); \
                       a2 = fmaf(sc, bflo(v.y), a2); a3 = fmaf(sc, bfhi(v.y), a3); \
                       a4 = fmaf(sc, bflo(v.z), a4); a5 = fmaf(sc, bfhi(v.z), a5); \
                       a6 = fmaf(sc, bflo(v.w), a6); a7 = fmaf(sc, bfhi(v.w), a7); }

// ---------------- aggregate1: ns[s]=rsqrt(dego[s]) per edge + epilogue ----------------
__global__ __launch_bounds__(256) void k_agg1(const uint4* __restrict__ h1,
                                              const int* __restrict__ dego,
                                              const int* __restrict__ degi,
                                              const int* __restrict__ csrp,
                                              const float* __restrict__ b1,
                                              uint4* __restrict__ x2p){
  __shared__ float b1s[8];
  int tid = threadIdx.x;
  if (tid < 8) b1s[tid] = b1[tid];
  __syncthreads();
  if (tid >= 250) return;
  int n = blockIdx.x*25 + tid/10;
  int t = tid - (tid/10)*10;
  float a0=0,a1=0,a2=0,a3=0,a4=0,a5=0,a6=0,a7=0;
  int deg = degi[n]; if (deg > CAP) deg = CAP;
  const int* row = csrp + n*CAP;
  int j = 0;
  for (; j + 4 <= deg; j += 4){
    int s0 = row[j], s1 = row[j+1], s2 = row[j+2], s3 = row[j+3];
    float n0 = rdeg(dego[s0]), n1 = rdeg(dego[s1]);
    float n2 = rdeg(dego[s2]), n3 = rdeg(dego[s3]);
    uint4 v0 = h1[(long long)s0*10 + t];
    uint4 v1 = h1[(long long)s1*10 + t];
    uint4 v2 = h1[(long long)s2*10 + t];
    uint4 v3 = h1[(long long)s3*10 + t];
    ACC8S(v0, n0) ACC8S(v1, n1) ACC8S(v2, n2) ACC8S(v3, n3)
  }
  for (; j < deg; ++j){
    int s = row[j];
    float nsv = rdeg(dego[s]);
    uint4 v = h1[(long long)s*10 + t];
    ACC8S(v, nsv)
  }
  float sc  = rdeg(degi[n]);   // dst norm
  float osc = rdeg(dego[n]);   // layer-2 source-norm pre-scale folded in
  float o0 = fmaxf(a0*sc + b1s[0], 0.f)*osc;
  float o1 = fmaxf(a1*sc + b1s[1], 0.f)*osc;
  float o2 = fmaxf(a2*sc + b1s[2], 0.f)*osc;
  float o3 = fmaxf(a3*sc + b1s[3], 0.f)*osc;
  float o4 = fmaxf(a4*sc + b1s[4], 0.f)*osc;
  float o5 = fmaxf(a5*sc + b1s[5], 0.f)*osc;
  float o6 = fmaxf(a6*sc + b1s[6], 0.f)*osc;
  float o7 = fmaxf(a7*sc + b1s[7], 0.f)*osc;
  uint4 pk;
  pk.x = pack2(o0,o1); pk.y = pack2(o2,o3); pk.z = pack2(o4,o5); pk.w = pack2(o6,o7);
  x2p[(long long)n*10 + t] = pk;
}

// ---------------- aggregate2 + W2 epilogue + LSTM input projection (bf16 xg) ----------------
__global__ __launch_bounds__(256) void k_agg2(const uint4* __restrict__ x2p,
                                              const int* __restrict__ degi,
                                              const int* __restrict__ csrp,
                                              const float* __restrict__ W2,
                                              const float* __restrict__ b2,
                                              const float* __restrict__ Wih,
                                              const float* __restrict__ bih,
                                              const float* __restrict__ bhh,
                                              uint4* __restrict__ xg){
  __shared__ float w2[128];
  __shared__ float4 wih[128];
  __shared__ float bsum[32];
  __shared__ float b2s[16];
  int tid = threadIdx.x;
  if (tid < 128){ w2[tid] = W2[tid]; wih[tid] = ((const float4*)Wih)[tid]; }
  if (tid < 32) bsum[tid] = bih[tid] + bhh[tid];
  if (tid < 16) b2s[tid] = b2[tid];
  __syncthreads();
  if (tid >= 250) return;
  int nl = tid/10;
  int t  = tid - nl*10;
  int n = blockIdx.x*25 + nl;
  float a0=0,a1=0,a2=0,a3=0,a4=0,a5=0,a6=0,a7=0;
  int deg = degi[n]; if (deg > CAP) deg = CAP;
  const int* row = csrp + n*CAP;
  int j = 0;
  for (; j + 4 <= deg; j += 4){
    int s0 = row[j], s1 = row[j+1], s2 = row[j+2], s3 = row[j+3];
    uint4 v0 = x2p[(long long)s0*10 + t];
    uint4 v1 = x2p[(long long)s1*10 + t];
    uint4 v2 = x2p[(long long)s2*10 + t];
    uint4 v3 = x2p[(long long)s3*10 + t];
    ACC8(v0) ACC8(v1) ACC8(v2) ACC8(v3)
  }
  for (; j < deg; ++j){
    int s = row[j];
    uint4 v = x2p[(long long)s*10 + t];
    ACC8(v)
  }
  float sc = rdeg(degi[n]);
  float y[16];
  #pragma unroll
  for (int jj = 0; jj < 16; ++jj){
    float s = a0*w2[0*16+jj] + a1*w2[1*16+jj] + a2*w2[2*16+jj] + a3*w2[3*16+jj]
            + a4*w2[4*16+jj] + a5*w2[5*16+jj] + a6*w2[6*16+jj] + a7*w2[7*16+jj];
    y[jj] = fmaxf(s*sc + b2s[jj], 0.f);
  }
  uint4* outp = xg + ((long long)n*10 + t)*4;
  #pragma unroll
  for (int g8 = 0; g8 < 4; ++g8){
    float gv[8];
    #pragma unroll
    for (int c = 0; c < 8; ++c){
      int g = g8*8 + c;
      float s = bsum[g];
      #pragma unroll
      for (int q = 0; q < 4; ++q){
        float4 wv = wih[g*4 + q];
        s += y[q*4+0]*wv.x + y[q*4+1]*wv.y + y[q*4+2]*wv.z + y[q*4+3]*wv.w;
      }
      gv[c] = s;
    }
    uint4 pk;
    pk.x = pack2(gv[0],gv[1]); pk.y = pack2(gv[2],gv[3]);
    pk.z = pack2(gv[4],gv[5]); pk.w = pack2(gv[6],gv[7]);
    outp[g8] = pk;
  }
}

// ---------------- LSTM over T=10 + max-pool reduce + fused head (last block) ----------------
__global__ __launch_bounds__(256) void k_lstm(const uint4* __restrict__ xg,
                                              const float* __restrict__ Whh,
                                              unsigned* __restrict__ maxbuf,
                                              int* __restrict__ done,
                                              const float* __restrict__ Wo,
                                              const float* __restrict__ bo,
                                              float* __restrict__ out){
  __shared__ float4 whh[64];
  __shared__ unsigned smax[8];
  __shared__ int lastflag;
  int tid = threadIdx.x;
  if (tid < 64) whh[tid] = ((const float4*)Whh)[tid];
  if (tid < 8) smax[tid] = 0u;
  __syncthreads();
  int n = blockIdx.x*256 + tid;
  if (n < NN){
    float h[8] = {0,0,0,0,0,0,0,0};
    float c[8] = {0,0,0,0,0,0,0,0};
    const uint4* xr = xg + (long long)n*40;
    for (int t = 0; t < TW; ++t){
      float g[32];
      #pragma unroll
      for (int q = 0; q < 4; ++q){
        uint4 v = xr[t*4 + q];
        g[q*8+0]=bflo(v.x); g[q*8+1]=bfhi(v.x);
        g[q*8+2]=bflo(v.y); g[q*8+3]=bfhi(v.y);
        g[q*8+4]=bflo(v.z); g[q*8+5]=bfhi(v.z);
        g[q*8+6]=bflo(v.w); g[q*8+7]=bfhi(v.w);
      }
      #pragma unroll
      for (int gi = 0; gi < 32; ++gi){
        float4 wa = whh[gi*2+0], wb = whh[gi*2+1];
        g[gi] += h[0]*wa.x + h[1]*wa.y + h[2]*wa.z + h[3]*wa.w
               + h[4]*wb.x + h[5]*wb.y + h[6]*wb.z + h[7]*wb.w;
      }
      #pragma unroll
      for (int j = 0; j < 8; ++j){
        float ig = sigf(g[j]);
        float fg = sigf(g[8+j]);
        float gg = tanhfast(g[16+j]);
        float og = sigf(g[24+j]);
        c[j] = fg*c[j] + ig*gg;
        h[j] = og*tanhfast(c[j]);
      }
    }
    #pragma unroll
    for (int j = 0; j < 8; ++j){
      unsigned b = __float_as_uint(h[j]);
      unsigned u = (b & 0x80000000u) ? ~b : (b | 0x80000000u);
      atomicMax(&smax[j], u);
    }
  }
  __syncthreads();
  if (tid < 8) atomicMax(&maxbuf[tid], smax[tid]);
  __syncthreads();
  if (tid == 0){
    __threadfence();
    int prev = atomicAdd(done, 1);
    lastflag = (prev == LB - 1);
  }
  __syncthreads();
  if (lastflag && tid == 0){
    float m[8];
    #pragma unroll
    for (int j = 0; j < 8; ++j){
      unsigned u = atomicAdd(&maxbuf[j], 0u);
      unsigned b = (u & 0x80000000u) ? (u ^ 0x80000000u) : ~u;
      m[j] = __uint_as_float(b);
    }
    #pragma unroll
    for (int o = 0; o < 4; ++o){
      float s = bo[o];
      #pragma unroll
      for (int k = 0; k < 8; ++k) s += m[k]*Wo[k*4 + o];
      out[o] = 1.0f/(1.0f + __expf(-s));
    }
  }
}

extern "C" void kernel_launch(void* const* d_in, const int* in_sizes, int n_in,
                              void* d_out, int out_size, void* d_ws, size_t ws_size,
                              hipStream_t stream) {
  const float* feat = (const float*)d_in[0];
  const int*   src  = (const int*)d_in[1];
  const int*   dst  = (const int*)d_in[2];
  const float* W1   = (const float*)d_in[3];
  const float* b1   = (const float*)d_in[4];
  const float* W2   = (const float*)d_in[5];
  const float* b2   = (const float*)d_in[6];
  const float* Wih  = (const float*)d_in[7];
  const float* Whh  = (const float*)d_in[8];
  const float* bih  = (const float*)d_in[9];
  const float* bhh  = (const float*)d_in[10];
  const float* Wo   = (const float*)d_in[11];
  const float* bo   = (const float*)d_in[12];
  float* out = (float*)d_out;

  // workspace layout (ints)
  int*      base      = (int*)d_ws;
  int*      dego      = base;                     // [0, SNP)      zeroed
  int*      degi      = base + SNP;               // [SNP, 2SNP)   zeroed (cursor + in-degree)
  int*      spare     = base + 2*SNP;             // [2SNP, 3SNP)  zeroed; holds done
  int*      done      = spare + 50040;
  unsigned* maxbuf    = (unsigned*)(base + 3*SNP); // 8 used, 64 reserved
  int*      csrp      = (int*)(maxbuf + 64);       // 50000*80 = 4,000,000 ints (16 MB)
  uint4*    h1        = (uint4*)(csrp + NN*CAP);   // 8 MB  [n][t] raw conv1 out
  uint4*    x2p       = h1 + 500000;               // 8 MB  [n][t]
  uint4*    xg        = x2p + 500000;              // 32 MB [n][t][4]

  const int B = 256;
  k_zero     <<<(ZERO_U4 + B - 1)/B, B, 0, stream>>>((uint4*)d_ws, maxbuf);
  k_buildconv<<<TOTAL_B, B, 0, stream>>>(feat, W1, src, dst, dego, degi, csrp, h1);
  k_agg1     <<<NBLK, B, 0, stream>>>(h1, dego, degi, csrp, b1, x2p);
  k_agg2     <<<NBLK, B, 0, stream>>>(x2p, degi, csrp, W2, b2, Wih, bih, bhh, xg);
  k_lstm     <<<LB, B, 0, stream>>>(xg, Whh, maxbuf, done, Wo, bo, out);
}

// Round 19
// 251.918 us; speedup vs baseline: 1.0409x; 1.0409x over previous
//
#include <hip/hip_runtime.h>
#include <math.h>

#define NN 50000
#define NE 800000
#define TW 10
#define SNP 50048          // padded node stride (ints)
#define CAP 80             // padded CSR row capacity (max in-degree ~35 expected)
#define TOTAL_B 2048       // fused edge+conv grid (fully resident)
#define NBLK 2000          // 25-node work blocks for agg kernels
#define LB 196             // lstm blocks

static __device__ __forceinline__ float sigf(float x){ return 1.0f/(1.0f+__expf(-x)); }
static __device__ __forceinline__ float tanhfast(float x){
  float e2 = __expf(2.0f*x);
  return 1.0f - 2.0f/(e2 + 1.0f);
}
// bf16 pack/unpack (RNE)
static __device__ __forceinline__ unsigned f2bf(float f){
  unsigned u = __float_as_uint(f);
  return (u + 0x7FFFu + ((u>>16)&1u)) >> 16;
}
static __device__ __forceinline__ unsigned pack2(float a, float b){
  return f2bf(a) | (f2bf(b) << 16);
}
static __device__ __forceinline__ float bflo(unsigned u){ return __uint_as_float(u << 16); }
static __device__ __forceinline__ float bfhi(unsigned u){ return __uint_as_float(u & 0xFFFF0000u); }
static __device__ __forceinline__ float rdeg(int d){ return rsqrtf((float)(d < 1 ? 1 : d)); }

// ---------------- zero counters + init maxbuf ----------------
#define ZERO_U4 37536   // 3*SNP ints = 600576 B
__global__ void k_zero(uint4* __restrict__ p, unsigned* __restrict__ maxbuf){
  int i = blockIdx.x*256 + threadIdx.x;
  uint4 z; z.x = 0u; z.y = 0u; z.z = 0u; z.w = 0u;
  if (i < ZERO_U4) p[i] = z;
  if (i < 8) maxbuf[i] = 0x3FFFFFFFu;   // monotonic-map(-2.0f)
}

// ======= fused edge pass (degree + padded-CSR, ushort) -> conv1(raw) =======
// R17 fall-through form (measured best). csrp is ushort: halves the gather
// kernels' CSR read footprint (16 MB -> 8 MB).
__global__ __launch_bounds__(256) void k_buildconv(const float* __restrict__ feat,
                                                   const float* __restrict__ W1,
                                                   const int* __restrict__ src,
                                                   const int* __restrict__ dst,
                                                   int* __restrict__ dego,
                                                   int* __restrict__ degi,
                                                   unsigned short* __restrict__ csrp,
                                                   uint4* __restrict__ h1){
  int tid = threadIdx.x;
  int gthread = blockIdx.x*256 + tid;
  // ---- phase 1: edges, int4-vectorized (NE/4 = 200000 items) ----
  {
    const int4* s4 = (const int4*)src;
    const int4* d4 = (const int4*)dst;
    const int NITEM = NE/4;
    for (int i = gthread; i < NITEM; i += TOTAL_B*256){
      int4 sv = s4[i];
      int4 dv = d4[i];
      int p0 = atomicAdd(&degi[dv.x], 1);
      int p1 = atomicAdd(&degi[dv.y], 1);
      int p2 = atomicAdd(&degi[dv.z], 1);
      int p3 = atomicAdd(&degi[dv.w], 1);
      if (p0 < CAP) csrp[dv.x*CAP + p0] = (unsigned short)sv.x;
      if (p1 < CAP) csrp[dv.y*CAP + p1] = (unsigned short)sv.y;
      if (p2 < CAP) csrp[dv.z*CAP + p2] = (unsigned short)sv.z;
      if (p3 < CAP) csrp[dv.w*CAP + p3] = (unsigned short)sv.w;
      atomicAdd(&dego[sv.x], 1);
      atomicAdd(&dego[sv.y], 1);
      atomicAdd(&dego[sv.z], 1);
      atomicAdd(&dego[sv.w], 1);
    }
  }
  // ---- phase 2: conv1 raw (16 lanes per row, weights in VGPRs from global) ----
  int lane = tid & 15;
  float4 wa[8], wb[8];
  #pragma unroll
  for (int d = 0; d < 8; ++d){
    wa[d] = ((const float4*)W1)[(lane*8 + d)*2 + 0];
    wb[d] = ((const float4*)W1)[(lane*8 + d)*2 + 1];
  }
  int gid = gthread >> 4;
  const int ngroups = TOTAL_B*16;
  for (int r = gid; r < TW*NN; r += ngroups){
    const float4* frow = (const float4*)feat + (long long)r*32 + lane*2;
    float4 f0 = frow[0], f1 = frow[1];
    float fs[8] = {f0.x,f0.y,f0.z,f0.w,f1.x,f1.y,f1.z,f1.w};
    float acc[8] = {0,0,0,0,0,0,0,0};
    #pragma unroll
    for (int d = 0; d < 8; ++d){
      float fv = fs[d];
      acc[0] += fv*wa[d].x; acc[1] += fv*wa[d].y; acc[2] += fv*wa[d].z; acc[3] += fv*wa[d].w;
      acc[4] += fv*wb[d].x; acc[5] += fv*wb[d].y; acc[6] += fv*wb[d].z; acc[7] += fv*wb[d].w;
    }
    int b8 = (lane>>3)&1, b4 = (lane>>2)&1, b2 = (lane>>1)&1;
    float s0 = b8 ? acc[0] : acc[4], s1 = b8 ? acc[1] : acc[5];
    float s2 = b8 ? acc[2] : acc[6], s3 = b8 ? acc[3] : acc[7];
    float k0 = b8 ? acc[4] : acc[0], k1 = b8 ? acc[5] : acc[1];
    float k2 = b8 ? acc[6] : acc[2], k3 = b8 ? acc[7] : acc[3];
    k0 += __shfl_xor(s0, 8); k1 += __shfl_xor(s1, 8);
    k2 += __shfl_xor(s2, 8); k3 += __shfl_xor(s3, 8);
    float t0 = b4 ? k0 : k2, t1 = b4 ? k1 : k3;
    float m0 = b4 ? k2 : k0, m1 = b4 ? k3 : k1;
    m0 += __shfl_xor(t0, 4); m1 += __shfl_xor(t1, 4);
    float u1 = b2 ? m0 : m1;
    float v0 = b2 ? m1 : m0;
    v0 += __shfl_xor(u1, 2);
    v0 += __shfl_xor(v0, 1);
    int t = r / NN;
    int n = r - t*NN;
    unsigned u = f2bf(v0) << (b2*16);     // raw: ns applied per-edge in agg1
    u |= __shfl_xor(u, 2);
    if ((lane & 3) == 0){
      int kk = b8*2 + b4;
      ((unsigned*)h1)[((long long)n*10 + t)*4 + kk] = u;
    }
  }
}

// ======= gather kernels: block = 25 nodes x 10 windows, padded-CSR (ushort) =======
#define ACC8(v) { a0 += bflo(v.x); a1 += bfhi(v.x); a2 += bflo(v.y); a3 += bfhi(v.y); \
                  a4 += bflo(v.z); a5 += bfhi(v.z); a6 += bflo(v.w); a7 += bfhi(v.w); }
#define ACC8S(v, sc) { a0 = fmaf(sc, bflo(v.x), a0); a1 = fmaf(sc, bfhi(v.x), a1); \
                       a2 = fmaf(sc, bflo(v.y), a2); a3 = fmaf(sc, bfhi(v.y), a3); \
                       a4 = fmaf(sc, bflo(v.z), a4); a5 = fmaf(sc, bfhi(v.z), a5); \
                       a6 = fmaf(sc, bflo(v.w), a6); a7 = fmaf(sc, bfhi(v.w), a7); }

// ---------------- aggregate1: ns[s]=rsqrt(dego[s]) per edge + epilogue ----------------
__global__ __launch_bounds__(256) void k_agg1(const uint4* __restrict__ h1,
                                              const int* __restrict__ dego,
                                              const int* __restrict__ degi,
                                              const unsigned short* __restrict__ csrp,
                                              const float* __restrict__ b1,
                                              uint4* __restrict__ x2p){
  __shared__ float b1s[8];
  int tid = threadIdx.x;
  if (tid < 8) b1s[tid] = b1[tid];
  __syncthreads();
  if (tid >= 250) return;
  int n = blockIdx.x*25 + tid/10;
  int t = tid - (tid/10)*10;
  float a0=0,a1=0,a2=0,a3=0,a4=0,a5=0,a6=0,a7=0;
  int deg = degi[n]; if (deg > CAP) deg = CAP;
  const unsigned short* row = csrp + n*CAP;
  int j = 0;
  for (; j + 4 <= deg; j += 4){
    int s0 = row[j], s1 = row[j+1], s2 = row[j+2], s3 = row[j+3];
    float n0 = rdeg(dego[s0]), n1 = rdeg(dego[s1]);
    float n2 = rdeg(dego[s2]), n3 = rdeg(dego[s3]);
    uint4 v0 = h1[(long long)s0*10 + t];
    uint4 v1 = h1[(long long)s1*10 + t];
    uint4 v2 = h1[(long long)s2*10 + t];
    uint4 v3 = h1[(long long)s3*10 + t];
    ACC8S(v0, n0) ACC8S(v1, n1) ACC8S(v2, n2) ACC8S(v3, n3)
  }
  for (; j < deg; ++j){
    int s = row[j];
    float nsv = rdeg(dego[s]);
    uint4 v = h1[(long long)s*10 + t];
    ACC8S(v, nsv)
  }
  float sc  = rdeg(degi[n]);   // dst norm
  float osc = rdeg(dego[n]);   // layer-2 source-norm pre-scale folded in
  float o0 = fmaxf(a0*sc + b1s[0], 0.f)*osc;
  float o1 = fmaxf(a1*sc + b1s[1], 0.f)*osc;
  float o2 = fmaxf(a2*sc + b1s[2], 0.f)*osc;
  float o3 = fmaxf(a3*sc + b1s[3], 0.f)*osc;
  float o4 = fmaxf(a4*sc + b1s[4], 0.f)*osc;
  float o5 = fmaxf(a5*sc + b1s[5], 0.f)*osc;
  float o6 = fmaxf(a6*sc + b1s[6], 0.f)*osc;
  float o7 = fmaxf(a7*sc + b1s[7], 0.f)*osc;
  uint4 pk;
  pk.x = pack2(o0,o1); pk.y = pack2(o2,o3); pk.z = pack2(o4,o5); pk.w = pack2(o6,o7);
  x2p[(long long)n*10 + t] = pk;
}

// ---------------- aggregate2 + W2 epilogue + LSTM input projection (bf16 xg) ----------------
__global__ __launch_bounds__(256) void k_agg2(const uint4* __restrict__ x2p,
                                              const int* __restrict__ degi,
                                              const unsigned short* __restrict__ csrp,
                                              const float* __restrict__ W2,
                                              const float* __restrict__ b2,
                                              const float* __restrict__ Wih,
                                              const float* __restrict__ bih,
                                              const float* __restrict__ bhh,
                                              uint4* __restrict__ xg){
  __shared__ float w2[128];
  __shared__ float4 wih[128];
  __shared__ float bsum[32];
  __shared__ float b2s[16];
  int tid = threadIdx.x;
  if (tid < 128){ w2[tid] = W2[tid]; wih[tid] = ((const float4*)Wih)[tid]; }
  if (tid < 32) bsum[tid] = bih[tid] + bhh[tid];
  if (tid < 16) b2s[tid] = b2[tid];
  __syncthreads();
  if (tid >= 250) return;
  int nl = tid/10;
  int t  = tid - nl*10;
  int n = blockIdx.x*25 + nl;
  float a0=0,a1=0,a2=0,a3=0,a4=0,a5=0,a6=0,a7=0;
  int deg = degi[n]; if (deg > CAP) deg = CAP;
  const unsigned short* row = csrp + n*CAP;
  int j = 0;
  for (; j + 4 <= deg; j += 4){
    int s0 = row[j], s1 = row[j+1], s2 = row[j+2], s3 = row[j+3];
    uint4 v0 = x2p[(long long)s0*10 + t];
    uint4 v1 = x2p[(long long)s1*10 + t];
    uint4 v2 = x2p[(long long)s2*10 + t];
    uint4 v3 = x2p[(long long)s3*10 + t];
    ACC8(v0) ACC8(v1) ACC8(v2) ACC8(v3)
  }
  for (; j < deg; ++j){
    int s = row[j];
    uint4 v = x2p[(long long)s*10 + t];
    ACC8(v)
  }
  float sc = rdeg(degi[n]);
  float y[16];
  #pragma unroll
  for (int jj = 0; jj < 16; ++jj){
    float s = a0*w2[0*16+jj] + a1*w2[1*16+jj] + a2*w2[2*16+jj] + a3*w2[3*16+jj]
            + a4*w2[4*16+jj] + a5*w2[5*16+jj] + a6*w2[6*16+jj] + a7*w2[7*16+jj];
    y[jj] = fmaxf(s*sc + b2s[jj], 0.f);
  }
  uint4* outp = xg + ((long long)n*10 + t)*4;
  #pragma unroll
  for (int g8 = 0; g8 < 4; ++g8){
    float gv[8];
    #pragma unroll
    for (int c = 0; c < 8; ++c){
      int g = g8*8 + c;
      float s = bsum[g];
      #pragma unroll
      for (int q = 0; q < 4; ++q){
        float4 wv = wih[g*4 + q];
        s += y[q*4+0]*wv.x + y[q*4+1]*wv.y + y[q*4+2]*wv.z + y[q*4+3]*wv.w;
      }
      gv[c] = s;
    }
    uint4 pk;
    pk.x = pack2(gv[0],gv[1]); pk.y = pack2(gv[2],gv[3]);
    pk.z = pack2(gv[4],gv[5]); pk.w = pack2(gv[6],gv[7]);
    outp[g8] = pk;
  }
}

// ---------------- LSTM over T=10 + max-pool reduce + fused head (last block) ----------------
__global__ __launch_bounds__(256) void k_lstm(const uint4* __restrict__ xg,
                                              const float* __restrict__ Whh,
                                              unsigned* __restrict__ maxbuf,
                                              int* __restrict__ done,
                                              const float* __restrict__ Wo,
                                              const float* __restrict__ bo,
                                              float* __restrict__ out){
  __shared__ float4 whh[64];
  __shared__ unsigned smax[8];
  __shared__ int lastflag;
  int tid = threadIdx.x;
  if (tid < 64) whh[tid] = ((const float4*)Whh)[tid];
  if (tid < 8) smax[tid] = 0u;
  __syncthreads();
  int n = blockIdx.x*256 + tid;
  if (n < NN){
    float h[8] = {0,0,0,0,0,0,0,0};
    float c[8] = {0,0,0,0,0,0,0,0};
    const uint4* xr = xg + (long long)n*40;
    for (int t = 0; t < TW; ++t){
      float g[32];
      #pragma unroll
      for (int q = 0; q < 4; ++q){
        uint4 v = xr[t*4 + q];
        g[q*8+0]=bflo(v.x); g[q*8+1]=bfhi(v.x);
        g[q*8+2]=bflo(v.y); g[q*8+3]=bfhi(v.y);
        g[q*8+4]=bflo(v.z); g[q*8+5]=bfhi(v.z);
        g[q*8+6]=bflo(v.w); g[q*8+7]=bfhi(v.w);
      }
      #pragma unroll
      for (int gi = 0; gi < 32; ++gi){
        float4 wa = whh[gi*2+0], wb = whh[gi*2+1];
        g[gi] += h[0]*wa.x + h[1]*wa.y + h[2]*wa.z + h[3]*wa.w
               + h[4]*wb.x + h[5]*wb.y + h[6]*wb.z + h[7]*wb.w;
      }
      #pragma unroll
      for (int j = 0; j < 8; ++j){
        float ig = sigf(g[j]);
        float fg = sigf(g[8+j]);
        float gg = tanhfast(g[16+j]);
        float og = sigf(g[24+j]);
        c[j] = fg*c[j] + ig*gg;
        h[j] = og*tanhfast(c[j]);
      }
    }
    #pragma unroll
    for (int j = 0; j < 8; ++j){
      unsigned b = __float_as_uint(h[j]);
      unsigned u = (b & 0x80000000u) ? ~b : (b | 0x80000000u);
      atomicMax(&smax[j], u);
    }
  }
  __syncthreads();
  if (tid < 8) atomicMax(&maxbuf[tid], smax[tid]);
  __syncthreads();
  if (tid == 0){
    __threadfence();
    int prev = atomicAdd(done, 1);
    lastflag = (prev == LB - 1);
  }
  __syncthreads();
  if (lastflag && tid == 0){
    float m[8];
    #pragma unroll
    for (int j = 0; j < 8; ++j){
      unsigned u = atomicAdd(&maxbuf[j], 0u);
      unsigned b = (u & 0x80000000u) ? (u ^ 0x80000000u) : ~u;
      m[j] = __uint_as_float(b);
    }
    #pragma unroll
    for (int o = 0; o < 4; ++o){
      float s = bo[o];
      #pragma unroll
      for (int k = 0; k < 8; ++k) s += m[k]*Wo[k*4 + o];
      out[o] = 1.0f/(1.0f + __expf(-s));
    }
  }
}

extern "C" void kernel_launch(void* const* d_in, const int* in_sizes, int n_in,
                              void* d_out, int out_size, void* d_ws, size_t ws_size,
                              hipStream_t stream) {
  const float* feat = (const float*)d_in[0];
  const int*   src  = (const int*)d_in[1];
  const int*   dst  = (const int*)d_in[2];
  const float* W1   = (const float*)d_in[3];
  const float* b1   = (const float*)d_in[4];
  const float* W2   = (const float*)d_in[5];
  const float* b2   = (const float*)d_in[6];
  const float* Wih  = (const float*)d_in[7];
  const float* Whh  = (const float*)d_in[8];
  const float* bih  = (const float*)d_in[9];
  const float* bhh  = (const float*)d_in[10];
  const float* Wo   = (const float*)d_in[11];
  const float* bo   = (const float*)d_in[12];
  float* out = (float*)d_out;

  // workspace layout (ints)
  int*            base   = (int*)d_ws;
  int*            dego   = base;                      // [0, SNP)      zeroed
  int*            degi   = base + SNP;                // [SNP, 2SNP)   zeroed (cursor + in-degree)
  int*            spare  = base + 2*SNP;              // [2SNP, 3SNP)  zeroed; holds done
  int*            done   = spare + 50040;
  unsigned*       maxbuf = (unsigned*)(base + 3*SNP); // 8 used, 64 reserved
  unsigned short* csrp   = (unsigned short*)(maxbuf + 64); // 50000*80 ushort = 8 MB
  uint4*          h1     = (uint4*)(csrp + NN*CAP);   // 8 MB  [n][t] raw conv1 out
  uint4*          x2p    = h1 + 500000;               // 8 MB  [n][t]
  uint4*          xg     = x2p + 500000;              // 32 MB [n][t][4]

  const int B = 256;
  k_zero     <<<(ZERO_U4 + B - 1)/B, B, 0, stream>>>((uint4*)d_ws, maxbuf);
  k_buildconv<<<TOTAL_B, B, 0, stream>>>(feat, W1, src, dst, dego, degi, csrp, h1);
  k_agg1     <<<NBLK, B, 0, stream>>>(h1, dego, degi, csrp, b1, x2p);
  k_agg2     <<<NBLK, B, 0, stream>>>(x2p, degi, csrp, W2, b2, Wih, bih, bhh, xg);
  k_lstm     <<<LB, B, 0, stream>>>(xg, Whh, maxbuf, done, Wo, bo, out);
}

// Round 20
// 248.202 us; speedup vs baseline: 1.0565x; 1.0150x over previous
//
#include <hip/hip_runtime.h>
#include <math.h>

#define NN 50000
#define NE 800000
#define TW 10
#define SNP 50048          // padded node stride (ints)
#define CAP 80             // padded CSR row capacity (max in-degree ~35 expected)
#define TOTAL_B 2048       // fused conv+edge grid (fully resident)
#define NBLK 2000          // 25-node work blocks for agg kernels
#define LB 196             // lstm blocks

static __device__ __forceinline__ float sigf(float x){ return 1.0f/(1.0f+__expf(-x)); }
static __device__ __forceinline__ float tanhfast(float x){
  float e2 = __expf(2.0f*x);
  return 1.0f - 2.0f/(e2 + 1.0f);
}
// bf16 pack/unpack (RNE)
static __device__ __forceinline__ unsigned f2bf(float f){
  unsigned u = __float_as_uint(f);
  return (u + 0x7FFFu + ((u>>16)&1u)) >> 16;
}
static __device__ __forceinline__ unsigned pack2(float a, float b){
  return f2bf(a) | (f2bf(b) << 16);
}
static __device__ __forceinline__ float bflo(unsigned u){ return __uint_as_float(u << 16); }
static __device__ __forceinline__ float bfhi(unsigned u){ return __uint_as_float(u & 0xFFFF0000u); }
static __device__ __forceinline__ float rdeg(int d){ return rsqrtf((float)(d < 1 ? 1 : d)); }

// ---------------- zero counters + init maxbuf ----------------
#define ZERO_U4 37536   // 3*SNP ints = 600576 B
__global__ void k_zero(uint4* __restrict__ p, unsigned* __restrict__ maxbuf){
  int i = blockIdx.x*256 + threadIdx.x;
  uint4 z; z.x = 0u; z.y = 0u; z.z = 0u; z.w = 0u;
  if (i < ZERO_U4) p[i] = z;
  if (i < 8) maxbuf[i] = 0x3FFFFFFFu;   // monotonic-map(-2.0f)
}

// ======= fused: conv1(raw) FIRST (clean HBM streaming) -> edge pass second =======
// Conv streams feat at full BW before the atomic queue exists; the edge pass
// (degree + padded-CSR, ushort) then runs scalar (1-2 edges/thread) so each
// wave's dependent atomic->store chain is 1 deep, spread over all 524K threads.
__global__ __launch_bounds__(256) void k_buildconv(const float* __restrict__ feat,
                                                   const float* __restrict__ W1,
                                                   const int* __restrict__ src,
                                                   const int* __restrict__ dst,
                                                   int* __restrict__ dego,
                                                   int* __restrict__ degi,
                                                   unsigned short* __restrict__ csrp,
                                                   uint4* __restrict__ h1){
  int tid = threadIdx.x;
  int gthread = blockIdx.x*256 + tid;

  // ---- phase 1: conv1 raw (16 lanes per row, weights in VGPRs from global) ----
  {
    int lane = tid & 15;
    float4 wa[8], wb[8];
    #pragma unroll
    for (int d = 0; d < 8; ++d){
      wa[d] = ((const float4*)W1)[(lane*8 + d)*2 + 0];
      wb[d] = ((const float4*)W1)[(lane*8 + d)*2 + 1];
    }
    int gid = gthread >> 4;
    const int ngroups = TOTAL_B*16;
    for (int r = gid; r < TW*NN; r += ngroups){
      const float4* frow = (const float4*)feat + (long long)r*32 + lane*2;
      float4 f0 = frow[0], f1 = frow[1];
      float fs[8] = {f0.x,f0.y,f0.z,f0.w,f1.x,f1.y,f1.z,f1.w};
      float acc[8] = {0,0,0,0,0,0,0,0};
      #pragma unroll
      for (int d = 0; d < 8; ++d){
        float fv = fs[d];
        acc[0] += fv*wa[d].x; acc[1] += fv*wa[d].y; acc[2] += fv*wa[d].z; acc[3] += fv*wa[d].w;
        acc[4] += fv*wb[d].x; acc[5] += fv*wb[d].y; acc[6] += fv*wb[d].z; acc[7] += fv*wb[d].w;
      }
      int b8 = (lane>>3)&1, b4 = (lane>>2)&1, b2 = (lane>>1)&1;
      float s0 = b8 ? acc[0] : acc[4], s1 = b8 ? acc[1] : acc[5];
      float s2 = b8 ? acc[2] : acc[6], s3 = b8 ? acc[3] : acc[7];
      float k0 = b8 ? acc[4] : acc[0], k1 = b8 ? acc[5] : acc[1];
      float k2 = b8 ? acc[6] : acc[2], k3 = b8 ? acc[7] : acc[3];
      k0 += __shfl_xor(s0, 8); k1 += __shfl_xor(s1, 8);
      k2 += __shfl_xor(s2, 8); k3 += __shfl_xor(s3, 8);
      float t0 = b4 ? k0 : k2, t1 = b4 ? k1 : k3;
      float m0 = b4 ? k2 : k0, m1 = b4 ? k3 : k1;
      m0 += __shfl_xor(t0, 4); m1 += __shfl_xor(t1, 4);
      float u1 = b2 ? m0 : m1;
      float v0 = b2 ? m1 : m0;
      v0 += __shfl_xor(u1, 2);
      v0 += __shfl_xor(v0, 1);
      int t = r / NN;
      int n = r - t*NN;
      unsigned u = f2bf(v0) << (b2*16);     // raw: ns applied per-edge in agg1
      u |= __shfl_xor(u, 2);
      if ((lane & 3) == 0){
        int kk = b8*2 + b4;
        ((unsigned*)h1)[((long long)n*10 + t)*4 + kk] = u;
      }
    }
  }

  // ---- phase 2: edge pass, scalar (1-2 edges/thread) ----
  for (int e = gthread; e < NE; e += TOTAL_B*256){
    int d = dst[e];
    int s = src[e];
    int p = atomicAdd(&degi[d], 1);
    if (p < CAP) csrp[d*CAP + p] = (unsigned short)s;
    atomicAdd(&dego[s], 1);
  }
}

// ======= gather kernels: block = 25 nodes x 10 windows, padded-CSR (ushort) =======
#define ACC8(v) { a0 += bflo(v.x); a1 += bfhi(v.x); a2 += bflo(v.y); a3 += bfhi(v.y); \
                  a4 += bflo(v.z); a5 += bfhi(v.z); a6 += bflo(v.w); a7 += bfhi(v.w); }
#define ACC8S(v, sc) { a0 = fmaf(sc, bflo(v.x), a0); a1 = fmaf(sc, bfhi(v.x), a1); \
                       a2 = fmaf(sc, bflo(v.y), a2); a3 = fmaf(sc, bfhi(v.y), a3); \
                       a4 = fmaf(sc, bflo(v.z), a4); a5 = fmaf(sc, bfhi(v.z), a5); \
                       a6 = fmaf(sc, bflo(v.w), a6); a7 = fmaf(sc, bfhi(v.w), a7); }

// ---------------- aggregate1: ns[s]=rsqrt(dego[s]) per edge + epilogue ----------------
__global__ __launch_bounds__(256) void k_agg1(const uint4* __restrict__ h1,
                                              const int* __restrict__ dego,
                                              const int* __restrict__ degi,
                                              const unsigned short* __restrict__ csrp,
                                              const float* __restrict__ b1,
                                              uint4* __restrict__ x2p){
  __shared__ float b1s[8];
  int tid = threadIdx.x;
  if (tid < 8) b1s[tid] = b1[tid];
  __syncthreads();
  if (tid >= 250) return;
  int n = blockIdx.x*25 + tid/10;
  int t = tid - (tid/10)*10;
  float a0=0,a1=0,a2=0,a3=0,a4=0,a5=0,a6=0,a7=0;
  int deg = degi[n]; if (deg > CAP) deg = CAP;
  const unsigned short* row = csrp + n*CAP;
  int j = 0;
  for (; j + 4 <= deg; j += 4){
    int s0 = row[j], s1 = row[j+1], s2 = row[j+2], s3 = row[j+3];
    float n0 = rdeg(dego[s0]), n1 = rdeg(dego[s1]);
    float n2 = rdeg(dego[s2]), n3 = rdeg(dego[s3]);
    uint4 v0 = h1[(long long)s0*10 + t];
    uint4 v1 = h1[(long long)s1*10 + t];
    uint4 v2 = h1[(long long)s2*10 + t];
    uint4 v3 = h1[(long long)s3*10 + t];
    ACC8S(v0, n0) ACC8S(v1, n1) ACC8S(v2, n2) ACC8S(v3, n3)
  }
  for (; j < deg; ++j){
    int s = row[j];
    float nsv = rdeg(dego[s]);
    uint4 v = h1[(long long)s*10 + t];
    ACC8S(v, nsv)
  }
  float sc  = rdeg(degi[n]);   // dst norm
  float osc = rdeg(dego[n]);   // layer-2 source-norm pre-scale folded in
  float o0 = fmaxf(a0*sc + b1s[0], 0.f)*osc;
  float o1 = fmaxf(a1*sc + b1s[1], 0.f)*osc;
  float o2 = fmaxf(a2*sc + b1s[2], 0.f)*osc;
  float o3 = fmaxf(a3*sc + b1s[3], 0.f)*osc;
  float o4 = fmaxf(a4*sc + b1s[4], 0.f)*osc;
  float o5 = fmaxf(a5*sc + b1s[5], 0.f)*osc;
  float o6 = fmaxf(a6*sc + b1s[6], 0.f)*osc;
  float o7 = fmaxf(a7*sc + b1s[7], 0.f)*osc;
  uint4 pk;
  pk.x = pack2(o0,o1); pk.y = pack2(o2,o3); pk.z = pack2(o4,o5); pk.w = pack2(o6,o7);
  x2p[(long long)n*10 + t] = pk;
}

// ---------------- aggregate2 + W2 epilogue + LSTM input projection (bf16 xg) ----------------
__global__ __launch_bounds__(256) void k_agg2(const uint4* __restrict__ x2p,
                                              const int* __restrict__ degi,
                                              const unsigned short* __restrict__ csrp,
                                              const float* __restrict__ W2,
                                              const float* __restrict__ b2,
                                              const float* __restrict__ Wih,
                                              const float* __restrict__ bih,
                                              const float* __restrict__ bhh,
                                              uint4* __restrict__ xg){
  __shared__ float w2[128];
  __shared__ float4 wih[128];
  __shared__ float bsum[32];
  __shared__ float b2s[16];
  int tid = threadIdx.x;
  if (tid < 128){ w2[tid] = W2[tid]; wih[tid] = ((const float4*)Wih)[tid]; }
  if (tid < 32) bsum[tid] = bih[tid] + bhh[tid];
  if (tid < 16) b2s[tid] = b2[tid];
  __syncthreads();
  if (tid >= 250) return;
  int nl = tid/10;
  int t  = tid - nl*10;
  int n = blockIdx.x*25 + nl;
  float a0=0,a1=0,a2=0,a3=0,a4=0,a5=0,a6=0,a7=0;
  int deg = degi[n]; if (deg > CAP) deg = CAP;
  const unsigned short* row = csrp + n*CAP;
  int j = 0;
  for (; j + 4 <= deg; j += 4){
    int s0 = row[j], s1 = row[j+1], s2 = row[j+2], s3 = row[j+3];
    uint4 v0 = x2p[(long long)s0*10 + t];
    uint4 v1 = x2p[(long long)s1*10 + t];
    uint4 v2 = x2p[(long long)s2*10 + t];
    uint4 v3 = x2p[(long long)s3*10 + t];
    ACC8(v0) ACC8(v1) ACC8(v2) ACC8(v3)
  }
  for (; j < deg; ++j){
    int s = row[j];
    uint4 v = x2p[(long long)s*10 + t];
    ACC8(v)
  }
  float sc = rdeg(degi[n]);
  float y[16];
  #pragma unroll
  for (int jj = 0; jj < 16; ++jj){
    float s = a0*w2[0*16+jj] + a1*w2[1*16+jj] + a2*w2[2*16+jj] + a3*w2[3*16+jj]
            + a4*w2[4*16+jj] + a5*w2[5*16+jj] + a6*w2[6*16+jj] + a7*w2[7*16+jj];
    y[jj] = fmaxf(s*sc + b2s[jj], 0.f);
  }
  uint4* outp = xg + ((long long)n*10 + t)*4;
  #pragma unroll
  for (int g8 = 0; g8 < 4; ++g8){
    float gv[8];
    #pragma unroll
    for (int c = 0; c < 8; ++c){
      int g = g8*8 + c;
      float s = bsum[g];
      #pragma unroll
      for (int q = 0; q < 4; ++q){
        float4 wv = wih[g*4 + q];
        s += y[q*4+0]*wv.x + y[q*4+1]*wv.y + y[q*4+2]*wv.z + y[q*4+3]*wv.w;
      }
      gv[c] = s;
    }
    uint4 pk;
    pk.x = pack2(gv[0],gv[1]); pk.y = pack2(gv[2],gv[3]);
    pk.z = pack2(gv[4],gv[5]); pk.w = pack2(gv[6],gv[7]);
    outp[g8] = pk;
  }
}

// ---------------- LSTM over T=10 + max-pool reduce + fused head (last block) ----------------
__global__ __launch_bounds__(256) void k_lstm(const uint4* __restrict__ xg,
                                              const float* __restrict__ Whh,
                                              unsigned* __restrict__ maxbuf,
                                              int* __restrict__ done,
                                              const float* __restrict__ Wo,
                                              const float* __restrict__ bo,
                                              float* __restrict__ out){
  __shared__ float4 whh[64];
  __shared__ unsigned smax[8];
  __shared__ int lastflag;
  int tid = threadIdx.x;
  if (tid < 64) whh[tid] = ((const float4*)Whh)[tid];
  if (tid < 8) smax[tid] = 0u;
  __syncthreads();
  int n = blockIdx.x*256 + tid;
  if (n < NN){
    float h[8] = {0,0,0,0,0,0,0,0};
    float c[8] = {0,0,0,0,0,0,0,0};
    const uint4* xr = xg + (long long)n*40;
    for (int t = 0; t < TW; ++t){
      float g[32];
      #pragma unroll
      for (int q = 0; q < 4; ++q){
        uint4 v = xr[t*4 + q];
        g[q*8+0]=bflo(v.x); g[q*8+1]=bfhi(v.x);
        g[q*8+2]=bflo(v.y); g[q*8+3]=bfhi(v.y);
        g[q*8+4]=bflo(v.z); g[q*8+5]=bfhi(v.z);
        g[q*8+6]=bflo(v.w); g[q*8+7]=bfhi(v.w);
      }
      #pragma unroll
      for (int gi = 0; gi < 32; ++gi){
        float4 wa = whh[gi*2+0], wb = whh[gi*2+1];
        g[gi] += h[0]*wa.x + h[1]*wa.y + h[2]*wa.z + h[3]*wa.w
               + h[4]*wb.x + h[5]*wb.y + h[6]*wb.z + h[7]*wb.w;
      }
      #pragma unroll
      for (int j = 0; j < 8; ++j){
        float ig = sigf(g[j]);
        float fg = sigf(g[8+j]);
        float gg = tanhfast(g[16+j]);
        float og = sigf(g[24+j]);
        c[j] = fg*c[j] + ig*gg;
        h[j] = og*tanhfast(c[j]);
      }
    }
    #pragma unroll
    for (int j = 0; j < 8; ++j){
      unsigned b = __float_as_uint(h[j]);
      unsigned u = (b & 0x80000000u) ? ~b : (b | 0x80000000u);
      atomicMax(&smax[j], u);
    }
  }
  __syncthreads();
  if (tid < 8) atomicMax(&maxbuf[tid], smax[tid]);
  __syncthreads();
  if (tid == 0){
    __threadfence();
    int prev = atomicAdd(done, 1);
    lastflag = (prev == LB - 1);
  }
  __syncthreads();
  if (lastflag && tid == 0){
    float m[8];
    #pragma unroll
    for (int j = 0; j < 8; ++j){
      unsigned u = atomicAdd(&maxbuf[j], 0u);
      unsigned b = (u & 0x80000000u) ? (u ^ 0x80000000u) : ~u;
      m[j] = __uint_as_float(b);
    }
    #pragma unroll
    for (int o = 0; o < 4; ++o){
      float s = bo[o];
      #pragma unroll
      for (int k = 0; k < 8; ++k) s += m[k]*Wo[k*4 + o];
      out[o] = 1.0f/(1.0f + __expf(-s));
    }
  }
}

extern "C" void kernel_launch(void* const* d_in, const int* in_sizes, int n_in,
                              void* d_out, int out_size, void* d_ws, size_t ws_size,
                              hipStream_t stream) {
  const float* feat = (const float*)d_in[0];
  const int*   src  = (const int*)d_in[1];
  const int*   dst  = (const int*)d_in[2];
  const float* W1   = (const float*)d_in[3];
  const float* b1   = (const float*)d_in[4];
  const float* W2   = (const float*)d_in[5];
  const float* b2   = (const float*)d_in[6];
  const float* Wih  = (const float*)d_in[7];
  const float* Whh  = (const float*)d_in[8];
  const float* bih  = (const float*)d_in[9];
  const float* bhh  = (const float*)d_in[10];
  const float* Wo   = (const float*)d_in[11];
  const float* bo   = (const float*)d_in[12];
  float* out = (float*)d_out;

  // workspace layout (ints)
  int*            base   = (int*)d_ws;
  int*            dego   = base;                      // [0, SNP)      zeroed
  int*            degi   = base + SNP;                // [SNP, 2SNP)   zeroed (cursor + in-degree)
  int*            spare  = base + 2*SNP;              // [2SNP, 3SNP)  zeroed; holds done
  int*            done   = spare + 50040;
  unsigned*       maxbuf = (unsigned*)(base + 3*SNP); // 8 used, 64 reserved
  unsigned short* csrp   = (unsigned short*)(maxbuf + 64); // 50000*80 ushort = 8 MB
  uint4*          h1     = (uint4*)(csrp + NN*CAP);   // 8 MB  [n][t] raw conv1 out
  uint4*          x2p    = h1 + 500000;               // 8 MB  [n][t]
  uint4*          xg     = x2p + 500000;              // 32 MB [n][t][4]

  const int B = 256;
  k_zero     <<<(ZERO_U4 + B - 1)/B, B, 0, stream>>>((uint4*)d_ws, maxbuf);
  k_buildconv<<<TOTAL_B, B, 0, stream>>>(feat, W1, src, dst, dego, degi, csrp, h1);
  k_agg1     <<<NBLK, B, 0, stream>>>(h1, dego, degi, csrp, b1, x2p);
  k_agg2     <<<NBLK, B, 0, stream>>>(x2p, degi, csrp, W2, b2, Wih, bih, bhh, xg);
  k_lstm     <<<LB, B, 0, stream>>>(xg, Whh, maxbuf, done, Wo, bo, out);
}